// Round 1
// baseline (120.597 us; speedup 1.0000x reference)
//
#include <hip/hip_runtime.h>
#include <math.h>

#define H 1024
#define V 50257
#define S 2048
#define NCH 64            // s-chunks for context partial sums

// workspace layout (float offsets)
#define O_HDOT   0                         // 1
#define O_COEFF  64                        // S
#define O_CTXP   (O_COEFF + S)             // NCH*H
#define O_CTX    (O_CTXP + NCH*H)          // H
#define O_Z      (O_CTX + H)               // H
#define O_GATES  (O_Z + H)                 // 4H
#define O_HNEW   (O_GATES + 4*H)           // H
#define O_LOGITS (O_HNEW + H)              // V
#define O_PMAX   (((O_LOGITS + V) + 63) & ~63)  // 64
#define O_SCAL   (O_PMAX + 64)             // 2

__device__ inline float wave_reduce_sum(float v) {
    for (int off = 32; off > 0; off >>= 1) v += __shfl_down(v, off, 64);
    return v;
}
__device__ inline float wave_reduce_max(float v) {
    for (int off = 32; off > 0; off >>= 1) v = fmaxf(v, __shfl_down(v, off, 64));
    return v;
}

// --- 1. hdot = dot(h, attn_W[H:2H]) + attn_b  (scalar, constant over s) ---
__global__ void k_hdot(const float* __restrict__ h, const float* __restrict__ attn_W,
                       const float* __restrict__ attn_b, float* __restrict__ ws) {
    int t = threadIdx.x;                     // 256 threads
    float s = 0.f;
    for (int k = t; k < H; k += 256) s += h[k] * attn_W[H + k];
    __shared__ float red[4];
    s = wave_reduce_sum(s);
    if ((t & 63) == 0) red[t >> 6] = s;
    __syncthreads();
    if (t == 0) ws[O_HDOT] = red[0] + red[1] + red[2] + red[3] + attn_b[0];
}

// --- 2. coeff[s] = dot(enc[s], attn_W[0:H]) + hdot ---
__global__ void k_coeff(const float* __restrict__ enc, const float* __restrict__ attn_W,
                        float* __restrict__ ws) {
    int sidx = blockIdx.x;                   // one block per s
    int t = threadIdx.x;                     // 256 threads, float4 each
    const float4* erow = (const float4*)(enc + (size_t)sidx * H);
    const float4* wrow = (const float4*)attn_W;
    float4 e = erow[t];
    float4 w = wrow[t];
    float s = e.x*w.x + e.y*w.y + e.z*w.z + e.w*w.w;
    __shared__ float red[4];
    s = wave_reduce_sum(s);
    if ((t & 63) == 0) red[t >> 6] = s;
    __syncthreads();
    if (t == 0) ws[O_COEFF + sidx] = red[0] + red[1] + red[2] + red[3] + ws[O_HDOT];
}

// --- 3. context partials: ctxp[ch][j] = sum_{s in chunk ch} enc[s][j]*coeff[s] ---
__global__ void k_ctxp(const float* __restrict__ enc, float* __restrict__ ws) {
    int j  = blockIdx.x * 256 + threadIdx.x; // [0,1024)
    int ch = blockIdx.y;                     // [0,NCH)
    const int SPC = S / NCH;                 // 32
    const float* coeff = ws + O_COEFF;
    float acc = 0.f;
    int s0 = ch * SPC;
    for (int s = s0; s < s0 + SPC; ++s)
        acc += enc[(size_t)s * H + j] * coeff[s];
    ws[O_CTXP + ch * H + j] = acc;
}

// --- 4. context reduce over chunks ---
__global__ void k_ctx(float* __restrict__ ws) {
    int j = blockIdx.x * 256 + threadIdx.x;
    float acc = 0.f;
    for (int ch = 0; ch < NCH; ++ch) acc += ws[O_CTXP + ch * H + j];
    ws[O_CTX + j] = acc;
}

// --- 5. z = relu(comb_W @ [x;ctx] + comb_b), wave per output row ---
__global__ void k_z(const float* __restrict__ emb, const int* __restrict__ ids,
                    const float* __restrict__ comb_W, const float* __restrict__ comb_b,
                    float* __restrict__ ws) {
    int i = blockIdx.x * 4 + (threadIdx.x >> 6);   // [0,1024)
    int lane = threadIdx.x & 63;
    int tok = ids[0];
    const float* x   = emb + (size_t)tok * H;
    const float* ctx = ws + O_CTX;
    const float4* wrow = (const float4*)(comb_W + (size_t)i * 2 * H);
    float s = 0.f;
    #pragma unroll
    for (int kk = 0; kk < 8; ++kk) {
        int k4 = kk * 64 + lane;                   // float4 index, row has 512
        float4 w = wrow[k4];
        int k = k4 * 4;
        const float* a = (k < H) ? (x + k) : (ctx + (k - H));
        float4 av = *(const float4*)a;
        s += w.x*av.x + w.y*av.y + w.z*av.z + w.w*av.w;
    }
    s = wave_reduce_sum(s);
    if (lane == 0) ws[O_Z + i] = fmaxf(s + comb_b[i], 0.f);
}

// --- 6. gates = W_ih@z + b_ih + W_hh@h + b_hh, wave per output row ---
__global__ void k_gates(const float* __restrict__ W_ih, const float* __restrict__ W_hh,
                        const float* __restrict__ b_ih, const float* __restrict__ b_hh,
                        const float* __restrict__ h, float* __restrict__ ws) {
    int i = blockIdx.x * 4 + (threadIdx.x >> 6);   // [0,4096)
    int lane = threadIdx.x & 63;
    const float4* wi = (const float4*)(W_ih + (size_t)i * H);
    const float4* wh = (const float4*)(W_hh + (size_t)i * H);
    const float4* zv = (const float4*)(ws + O_Z);
    const float4* hv = (const float4*)h;
    float s = 0.f;
    #pragma unroll
    for (int kk = 0; kk < 4; ++kk) {
        int k4 = kk * 64 + lane;
        float4 a = wi[k4], b = zv[k4];
        s += a.x*b.x + a.y*b.y + a.z*b.z + a.w*b.w;
        float4 c2 = wh[k4], d = hv[k4];
        s += c2.x*d.x + c2.y*d.y + c2.z*d.z + c2.w*d.w;
    }
    s = wave_reduce_sum(s);
    if (lane == 0) ws[O_GATES + i] = s + b_ih[i] + b_hh[i];
}

// --- 7. LSTM pointwise; writes h_new/c_new to d_out tail and h_new to ws ---
__global__ void k_lstm(const float* __restrict__ c0, float* __restrict__ ws,
                       float* __restrict__ out) {
    int j = blockIdx.x * 256 + threadIdx.x;        // [0,1024)
    const float* g = ws + O_GATES;
    float ig = 1.f / (1.f + expf(-g[j]));
    float fg = 1.f / (1.f + expf(-g[H + j]));
    float gg = tanhf(g[2*H + j]);
    float og = 1.f / (1.f + expf(-g[3*H + j]));
    float cn = fg * c0[j] + ig * gg;
    float hn = og * tanhf(cn);
    out[V + j]      = hn;
    out[V + H + j]  = cn;
    ws[O_HNEW + j]  = hn;
}

// --- 8. logits = out_W @ h_new + out_b, wave per row (dominant kernel) ---
__global__ void k_logits(const float* __restrict__ out_W, const float* __restrict__ out_b,
                         float* __restrict__ ws) {
    int v = blockIdx.x * 4 + (threadIdx.x >> 6);
    if (v >= V) return;
    int lane = threadIdx.x & 63;
    const float4* w  = (const float4*)(out_W + (size_t)v * H);
    const float4* hv = (const float4*)(ws + O_HNEW);
    float s = 0.f;
    #pragma unroll
    for (int kk = 0; kk < 4; ++kk) {
        int k4 = kk * 64 + lane;
        float4 a = w[k4], b = hv[k4];
        s += a.x*b.x + a.y*b.y + a.z*b.z + a.w*b.w;
    }
    s = wave_reduce_sum(s);
    if (lane == 0) ws[O_LOGITS + v] = s + out_b[v];
}

// --- 9. per-block max partials over logits ---
__global__ void k_max(float* __restrict__ ws) {
    int t = blockIdx.x * 256 + threadIdx.x;
    float m = -1e30f;
    for (int v = t; v < V; v += 64 * 256) m = fmaxf(m, ws[O_LOGITS + v]);
    __shared__ float red[4];
    m = wave_reduce_max(m);
    if ((threadIdx.x & 63) == 0) red[threadIdx.x >> 6] = m;
    __syncthreads();
    if (threadIdx.x == 0)
        ws[O_PMAX + blockIdx.x] = fmaxf(fmaxf(red[0], red[1]), fmaxf(red[2], red[3]));
}

// --- 10. finish max, compute log-sum-exp ---
__global__ void k_lse(float* __restrict__ ws) {
    int t = threadIdx.x;                            // 256 threads
    __shared__ float sm;
    float m = -1e30f;
    if (t < 64) m = ws[O_PMAX + t];
    m = wave_reduce_max(m);
    if (t == 0) sm = m;
    __syncthreads();
    float maxv = sm;
    float s = 0.f;
    for (int v = t; v < V; v += 256) s += expf(ws[O_LOGITS + v] - maxv);
    __shared__ float red[4];
    s = wave_reduce_sum(s);
    if ((t & 63) == 0) red[t >> 6] = s;
    __syncthreads();
    if (t == 0) {
        ws[O_SCAL]     = maxv;
        ws[O_SCAL + 1] = logf(red[0] + red[1] + red[2] + red[3]);
    }
}

// --- 11. write logp to d_out[0:V) ---
__global__ void k_logp(const float* __restrict__ ws, float* __restrict__ out) {
    int v = blockIdx.x * 256 + threadIdx.x;
    if (v < V) out[v] = ws[O_LOGITS + v] - ws[O_SCAL] - ws[O_SCAL + 1];
}

extern "C" void kernel_launch(void* const* d_in, const int* in_sizes, int n_in,
                              void* d_out, int out_size, void* d_ws, size_t ws_size,
                              hipStream_t stream) {
    const int*   ids    = (const int*)  d_in[0];
    const float* h0     = (const float*)d_in[1];
    const float* c0     = (const float*)d_in[2];
    const float* enc    = (const float*)d_in[3];
    const float* emb    = (const float*)d_in[4];
    const float* attn_W = (const float*)d_in[5];
    const float* attn_b = (const float*)d_in[6];
    const float* comb_W = (const float*)d_in[7];
    const float* comb_b = (const float*)d_in[8];
    const float* W_ih   = (const float*)d_in[9];
    const float* W_hh   = (const float*)d_in[10];
    const float* b_ih   = (const float*)d_in[11];
    const float* b_hh   = (const float*)d_in[12];
    const float* out_W  = (const float*)d_in[13];
    const float* out_b  = (const float*)d_in[14];
    float* out = (float*)d_out;
    float* ws  = (float*)d_ws;

    k_hdot  <<<1, 256, 0, stream>>>(h0, attn_W, attn_b, ws);
    k_coeff <<<S, 256, 0, stream>>>(enc, attn_W, ws);
    k_ctxp  <<<dim3(H/256, NCH), 256, 0, stream>>>(enc, ws);
    k_ctx   <<<H/256, 256, 0, stream>>>(ws);
    k_z     <<<H/4, 256, 0, stream>>>(emb, ids, comb_W, comb_b, ws);
    k_gates <<<4*H/4, 256, 0, stream>>>(W_ih, W_hh, b_ih, b_hh, h0, ws);
    k_lstm  <<<H/256, 256, 0, stream>>>(c0, ws, out);
    k_logits<<<(V + 3)/4, 256, 0, stream>>>(out_W, out_b, ws);
    k_max   <<<64, 256, 0, stream>>>(ws);
    k_lse   <<<1, 256, 0, stream>>>(ws);
    k_logp  <<<(V + 255)/256, 256, 0, stream>>>(ws, out);
}